// Round 9
// baseline (2455.722 us; speedup 1.0000x reference)
//
#include <hip/hip_runtime.h>
#include <hip/hip_bf16.h>
#include <stdint.h>

typedef __bf16 bf16x8 __attribute__((ext_vector_type(8)));
typedef float  f32x4  __attribute__((ext_vector_type(4)));

#define IN_DIM  4096
#define OUT_DIM 4096
#define M_DIM   8192

#define AS1 __attribute__((address_space(1)))
#define AS3 __attribute__((address_space(3)))

static __device__ __forceinline__ void gload_lds16(const void* g, void* l) {
  __builtin_amdgcn_global_load_lds((const AS1 void*)g, (AS3 void*)l, 16, 0, 0);
}
static __device__ __forceinline__ float bf2f(unsigned short u) {
  union { uint32_t i; float f; } c; c.i = (uint32_t)u << 16; return c.f;
}
static __device__ __forceinline__ unsigned short f2bf(float f) {
  __hip_bfloat16 h = __float2bfloat16(f); return *(const unsigned short*)&h;
}

// ------- Pass 1: decode + row FWHT(4096) + SU*1/64, with fused x->bf16 convert -------
__global__ __launch_bounds__(256) void k_decode_fwht_row(
    const int* __restrict__ trellis, const float2* __restrict__ tlut,
    const float* __restrict__ SU, __hip_bfloat16* __restrict__ w,
    const float* __restrict__ x, __hip_bfloat16* __restrict__ xb)
{
  __shared__ float buf[4096];
  __shared__ int words[128];
  __shared__ float2 lut[1024];
  const int tid = threadIdx.x;
  const int r = blockIdx.x;

  // issue X loads early; latency hides under trellis/LUT load + decode
  float4 xv[8];
  #pragma unroll
  for (int rep = 0; rep < 4; ++rep) {
    size_t i = (((size_t)r * 4 + rep) * 256 + tid) * 8;
    xv[rep * 2]     = *(const float4*)(x + i);
    xv[rep * 2 + 1] = *(const float4*)(x + i + 4);
  }

  if (tid < 128) words[tid] = trellis[r * 128 + tid];
  for (int i = tid; i < 1024; i += 256) lut[i] = tlut[i];
  __syncthreads();

  {
    const int t  = tid;
    const int wi = t >> 4;
    const int sh = 30 - 2 * (t & 15);
    const unsigned mask = (t < 4) ? ((1u << (2 * t + 2)) - 1u) : 1023u;
    #pragma unroll
    for (int s = 0; s < 8; ++s) {
      unsigned lo = (unsigned)words[s * 16 + wi];
      unsigned hi = wi ? (unsigned)words[s * 16 + wi - 1] : 0u;
      unsigned long long comb = ((unsigned long long)hi << 32) | (unsigned long long)lo;
      unsigned st = ((unsigned)(comb >> sh)) & mask;
      float2 v = lut[st];
      buf[s * 512 + 2 * t]     = v.x + v.y;   // h=1 stage folded
      buf[s * 512 + 2 * t + 1] = v.x - v.y;
    }
  }
  __syncthreads();

  for (int h = 2; h < 4096; h <<= 1) {
    #pragma unroll
    for (int q = 0; q < 8; ++q) {
      int b = q * 256 + tid;
      int i = ((b & ~(h - 1)) << 1) | (b & (h - 1));
      float a = buf[i], c = buf[i + h];
      buf[i]     = a + c;
      buf[i + h] = a - c;
    }
    __syncthreads();
  }

  for (int it2 = 0; it2 < 2; ++it2) {
    int c0 = (it2 * 256 + tid) * 8;
    union { unsigned short us[8]; uint4 v; } p;
    #pragma unroll
    for (int e = 0; e < 8; ++e)
      p.us[e] = f2bf(buf[c0 + e] * SU[c0 + e] * 0.015625f);
    *(uint4*)(w + (size_t)r * IN_DIM + c0) = p.v;
  }

  #pragma unroll
  for (int rep = 0; rep < 4; ++rep) {
    size_t i = (((size_t)r * 4 + rep) * 256 + tid) * 8;
    float4 v0 = xv[rep * 2], v1 = xv[rep * 2 + 1];
    union { __hip_bfloat16 h[8]; uint4 u; } p;
    p.h[0] = __float2bfloat16(v0.x); p.h[1] = __float2bfloat16(v0.y);
    p.h[2] = __float2bfloat16(v0.z); p.h[3] = __float2bfloat16(v0.w);
    p.h[4] = __float2bfloat16(v1.x); p.h[5] = __float2bfloat16(v1.y);
    p.h[6] = __float2bfloat16(v1.z); p.h[7] = __float2bfloat16(v1.w);
    *(uint4*)(xb + i) = p.u;
  }
}

// ---------------- Pass 2a: FWHT64 over row-index low 6 bits (in place) ----------------
__global__ __launch_bounds__(256) void k_fwht64_lo(__hip_bfloat16* __restrict__ w)
{
  __shared__ float tile[64][65];
  const int tid = threadIdx.x;
  const int rb = blockIdx.y, cb = blockIdx.x;

  for (int it = 0; it < 2; ++it) {
    int chunk = it * 256 + tid;
    int rr = chunk >> 3, jc = chunk & 7;
    uint4 v = *(const uint4*)(w + (size_t)(rb * 64 + rr) * IN_DIM + cb * 64 + jc * 8);
    const unsigned short* u = (const unsigned short*)&v;
    #pragma unroll
    for (int e = 0; e < 8; ++e) tile[rr][jc * 8 + e] = bf2f(u[e]);
  }
  __syncthreads();

  const int c = tid & 63, qf = tid >> 6;
  for (int h = 1; h < 64; h <<= 1) {
    #pragma unroll
    for (int u = 0; u < 8; ++u) {
      int b = qf * 8 + u;
      int i = ((b & ~(h - 1)) << 1) | (b & (h - 1));
      float a = tile[i][c], d = tile[i + h][c];
      tile[i][c]     = a + d;
      tile[i + h][c] = a - d;
    }
    __syncthreads();
  }

  for (int it = 0; it < 2; ++it) {
    int chunk = it * 256 + tid;
    int rr = chunk >> 3, jc = chunk & 7;
    union { unsigned short us[8]; uint4 v; } p;
    #pragma unroll
    for (int e = 0; e < 8; ++e) p.us[e] = f2bf(tile[rr][jc * 8 + e]);
    *(uint4*)(w + (size_t)(rb * 64 + rr) * IN_DIM + cb * 64 + jc * 8) = p.v;
  }
}

// ---------------- Pass 2b: FWHT64 over row-index high 6 bits + SV * 1/64 ----------------
__global__ __launch_bounds__(256) void k_fwht64_hi(__hip_bfloat16* __restrict__ w,
                                                   const float* __restrict__ SV)
{
  __shared__ float tile[64][65];
  const int tid = threadIdx.x;
  const int r0 = blockIdx.y, cb = blockIdx.x;

  for (int it = 0; it < 2; ++it) {
    int chunk = it * 256 + tid;
    int r1 = chunk >> 3, jc = chunk & 7;
    uint4 v = *(const uint4*)(w + (size_t)(r0 + 64 * r1) * IN_DIM + cb * 64 + jc * 8);
    const unsigned short* u = (const unsigned short*)&v;
    #pragma unroll
    for (int e = 0; e < 8; ++e) tile[r1][jc * 8 + e] = bf2f(u[e]);
  }
  __syncthreads();

  const int c = tid & 63, qf = tid >> 6;
  for (int h = 1; h < 64; h <<= 1) {
    #pragma unroll
    for (int u = 0; u < 8; ++u) {
      int b = qf * 8 + u;
      int i = ((b & ~(h - 1)) << 1) | (b & (h - 1));
      float a = tile[i][c], d = tile[i + h][c];
      tile[i][c]     = a + d;
      tile[i + h][c] = a - d;
    }
    __syncthreads();
  }

  for (int it = 0; it < 2; ++it) {
    int chunk = it * 256 + tid;
    int r1 = chunk >> 3, jc = chunk & 7;
    int row = r0 + 64 * r1;
    float sv = SV[row] * 0.015625f;
    union { unsigned short us[8]; uint4 v; } p;
    #pragma unroll
    for (int e = 0; e < 8; ++e) p.us[e] = f2bf(tile[r1][jc * 8 + e] * sv);
    *(uint4*)(w + (size_t)row * IN_DIM + cb * 64 + jc * 8) = p.v;
  }
}

// ========== GEMM: 256x256, ONE phase per K-tile, race-free DMA discipline ============
// Invariant (inductive): entering phase(t), buf[(t+1)&1] holds COMPLETE tile t+1
// (every wave executed s_waitcnt vmcnt(0) for its t+1 stages before the prior BAR),
// and buf[t&1] is free to overwrite (all frag reads drained via lgkmcnt(0)+BAR).
// phase(t): {STAGE8(t+2 -> buf t&1); RD_ALL(t+1); MFMA(t); vmcnt(0)+lgkmcnt(0); BAR}.
// The vmcnt(0) is ~free: its 8 loads were issued ~2480 MFMA-cycles earlier (>> HBM 900).
#define GBM 256
#define GBN 256
#define GBK 64
#define NT  (IN_DIM / GBK)   // 64 K-tiles

__global__ __launch_bounds__(512, 1) void k_gemm256(
    const __hip_bfloat16* __restrict__ X,   // [8192][4096]
    const __hip_bfloat16* __restrict__ W,   // [4096][4096]
    float* __restrict__ out)                // [8192][4096]
{
  extern __shared__ __hip_bfloat16 smem[];  // 131072 B
  __hip_bfloat16* As = smem;                // [2][256*64]
  __hip_bfloat16* Bs = smem + 2 * 16384;

  const int tid  = threadIdx.x;
  const int lane = tid & 63;
  const int wave = tid >> 6;
  const int wm   = wave >> 2;       // 0..1 (M)
  const int wn   = wave & 3;        // 0..3 (N)
  const int lm   = lane & 15;
  const int lq   = lane >> 4;       // 0..3
  const int s_rw = tid >> 3;
  const int s_jj = tid & 7;

  // T1: bijective XCD swizzle (512 blocks)
  const int nwg  = gridDim.x * gridDim.y;
  const int cpx  = nwg >> 3;
  const int orig = blockIdx.y * gridDim.x + blockIdx.x;
  const int swz  = (orig & 7) * cpx + (orig >> 3);
  const int bx   = swz % gridDim.x;
  const int by   = swz / gridDim.x;
  const int m0 = by * GBM, n0 = bx * GBN;

  f32x4 acc[8][4] = {};

#define STAGE8(buf, kt) do {                                                  \
    _Pragma("unroll")                                                         \
    for (int u_ = 0; u_ < 4; ++u_) {                                          \
      int row_ = u_ * 64 + s_rw;                                              \
      int js_  = s_jj ^ (row_ & 7);                                           \
      gload_lds16(X + (size_t)(m0 + row_) * IN_DIM + (kt) * GBK + js_ * 8,    \
                  As + (buf) * 16384 + row_ * 64 + s_jj * 8);                 \
      gload_lds16(W + (size_t)(n0 + row_) * IN_DIM + (kt) * GBK + js_ * 8,    \
                  Bs + (buf) * 16384 + row_ * 64 + s_jj * 8);                 \
    }                                                                         \
  } while (0)

#define RD_ALL(FA, FB, BUF) do {                                              \
    const __hip_bfloat16* Ab_ = As + (BUF) * 16384;                           \
    const __hip_bfloat16* Bb_ = Bs + (BUF) * 16384;                           \
    _Pragma("unroll")                                                         \
    for (int mi2 = 0; mi2 < 8; ++mi2) {                                       \
      int r_ = wm * 128 + mi2 * 16 + lm;                                      \
      _Pragma("unroll")                                                       \
      for (int kk = 0; kk < 2; ++kk) {                                        \
        int q_ = kk * 4 + lq;                                                 \
        FA[mi2][kk] = *(const bf16x8*)(Ab_ + r_ * 64 + ((q_ ^ (r_ & 7)) << 3)); \
      }                                                                       \
    }                                                                         \
    _Pragma("unroll")                                                         \
    for (int ni2 = 0; ni2 < 4; ++ni2) {                                       \
      int r_ = wn * 64 + ni2 * 16 + lm;                                       \
      _Pragma("unroll")                                                       \
      for (int kk = 0; kk < 2; ++kk) {                                        \
        int q_ = kk * 4 + lq;                                                 \
        FB[ni2][kk] = *(const bf16x8*)(Bb_ + r_ * 64 + ((q_ ^ (r_ & 7)) << 3)); \
      }                                                                       \
    }                                                                         \
  } while (0)

#define MFMA_ALL(FA, FB) do {                                                 \
    _Pragma("unroll")                                                         \
    for (int mi2 = 0; mi2 < 8; ++mi2)                                         \
      _Pragma("unroll")                                                       \
      for (int ni2 = 0; ni2 < 4; ++ni2)                                       \
        _Pragma("unroll")                                                     \
        for (int kk = 0; kk < 2; ++kk)                                        \
          acc[mi2][ni2] = __builtin_amdgcn_mfma_f32_16x16x32_bf16(            \
              FA[mi2][kk], FB[ni2][kk], acc[mi2][ni2], 0, 0, 0);              \
  } while (0)

#define FENCE asm volatile("" ::: "memory")
#define BAR do { FENCE; __builtin_amdgcn_s_barrier(); FENCE; } while (0)
#define DRAIN_ALL do { asm volatile("s_waitcnt vmcnt(0) lgkmcnt(0)" ::: "memory"); } while (0)

  bf16x8 fa0[8][2], fb0[4][2], fa1[8][2], fb1[4][2];

  // prologue: stage tiles 0,1; drain BOTH (cross-wave invariant); read tile-0 frags
  STAGE8(0, 0);
  STAGE8(1, 1);
  RD_ALL(fa0, fb0, 0);   // reads own-wave-independent rows — must wait for all DMA:
  DRAIN_ALL;             // (drain placed after issue; reads re-ordered below barrier)
  BAR;
  // NOTE: RD_ALL above may sample buf0 before other waves' DMA landed; redo it now
  // that the invariant holds (cheap: L0-hot). This keeps the loop body uniform.
  RD_ALL(fa0, fb0, 0);
  asm volatile("s_waitcnt lgkmcnt(0)" ::: "memory");
  BAR;

  for (int it = 0; it < NT / 2; ++it) {
    const int t2 = (2 * it + 2 < NT) ? 2 * it + 2 : NT - 1;
    const int t3 = (2 * it + 3 < NT) ? 2 * it + 3 : NT - 1;

    // phase even (tile 2it): stage t2 -> buf0, read tile 2it+1 from buf1
    STAGE8(0, t2);
    RD_ALL(fa1, fb1, 1);
    __builtin_amdgcn_s_setprio(1);
    MFMA_ALL(fa0, fb0);
    __builtin_amdgcn_s_setprio(0);
    DRAIN_ALL;
    BAR;

    // phase odd (tile 2it+1): stage t3 -> buf1, read tile 2it+2 from buf0
    STAGE8(1, t3);
    RD_ALL(fa0, fb0, 0);
    __builtin_amdgcn_s_setprio(1);
    MFMA_ALL(fa1, fb1);
    __builtin_amdgcn_s_setprio(0);
    DRAIN_ALL;
    BAR;
  }

  // epilogue: C/D layout col = lane&15, row = (lane>>4)*4 + reg
  #pragma unroll
  for (int mi = 0; mi < 8; ++mi) {
    #pragma unroll
    for (int ni = 0; ni < 4; ++ni) {
      int col   = n0 + wn * 64 + ni * 16 + lm;
      int rbase = m0 + wm * 128 + mi * 16 + lq * 4;
      #pragma unroll
      for (int rg = 0; rg < 4; ++rg) {
        out[(size_t)(rbase + rg) * OUT_DIM + col] = acc[mi][ni][rg];
      }
    }
  }
#undef DRAIN_ALL
#undef BAR
#undef FENCE
#undef MFMA_ALL
#undef RD_ALL
#undef STAGE8
}

extern "C" void kernel_launch(void* const* d_in, const int* in_sizes, int n_in,
                              void* d_out, int out_size, void* d_ws, size_t ws_size,
                              hipStream_t stream) {
  (void)in_sizes; (void)n_in; (void)out_size; (void)ws_size;
  const float* x       = (const float*)d_in[0];
  const int*   trellis = (const int*)d_in[1];
  const float* tlut    = (const float*)d_in[2];
  const float* SU      = (const float*)d_in[3];
  const float* SV      = (const float*)d_in[4];
  float* out = (float*)d_out;

  __hip_bfloat16* Wd = (__hip_bfloat16*)d_ws;                                     // 32 MB
  __hip_bfloat16* Xb = (__hip_bfloat16*)((char*)d_ws + (size_t)32 * 1024 * 1024); // 64 MB

  k_decode_fwht_row<<<4096, 256, 0, stream>>>(trellis, (const float2*)tlut, SU, Wd, x, Xb);
  k_fwht64_lo<<<dim3(64, 64), 256, 0, stream>>>(Wd);
  k_fwht64_hi<<<dim3(64, 64), 256, 0, stream>>>(Wd, SV);

  hipFuncSetAttribute((const void*)k_gemm256,
                      hipFuncAttributeMaxDynamicSharedMemorySize, 131072);
  k_gemm256<<<dim3(IN_DIM / GBN, M_DIM / GBM), 512, 131072, stream>>>(Xb, Wd, out);
}

// Round 10
// 351.439 us; speedup vs baseline: 6.9876x; 6.9876x over previous
//
#include <hip/hip_runtime.h>
#include <hip/hip_bf16.h>
#include <stdint.h>

typedef __bf16 bf16x8 __attribute__((ext_vector_type(8)));
typedef float  f32x4  __attribute__((ext_vector_type(4)));

#define IN_DIM  4096
#define OUT_DIM 4096
#define M_DIM   8192

#define AS1 __attribute__((address_space(1)))
#define AS3 __attribute__((address_space(3)))

static __device__ __forceinline__ void gload_lds16(const void* g, void* l) {
  __builtin_amdgcn_global_load_lds((const AS1 void*)g, (AS3 void*)l, 16, 0, 0);
}
static __device__ __forceinline__ float bf2f(unsigned short u) {
  union { uint32_t i; float f; } c; c.i = (uint32_t)u << 16; return c.f;
}
static __device__ __forceinline__ unsigned short f2bf(float f) {
  __hip_bfloat16 h = __float2bfloat16(f); return *(const unsigned short*)&h;
}

// ------- Pass 1: decode + row FWHT(4096) + SU*1/64, with fused x->bf16 convert -------
__global__ __launch_bounds__(256) void k_decode_fwht_row(
    const int* __restrict__ trellis, const float2* __restrict__ tlut,
    const float* __restrict__ SU, __hip_bfloat16* __restrict__ w,
    const float* __restrict__ x, __hip_bfloat16* __restrict__ xb)
{
  __shared__ float buf[4096];
  __shared__ int words[128];
  __shared__ float2 lut[1024];
  const int tid = threadIdx.x;
  const int r = blockIdx.x;

  // issue X loads early; latency hides under trellis/LUT load + decode
  float4 xv[8];
  #pragma unroll
  for (int rep = 0; rep < 4; ++rep) {
    size_t i = (((size_t)r * 4 + rep) * 256 + tid) * 8;
    xv[rep * 2]     = *(const float4*)(x + i);
    xv[rep * 2 + 1] = *(const float4*)(x + i + 4);
  }

  if (tid < 128) words[tid] = trellis[r * 128 + tid];
  for (int i = tid; i < 1024; i += 256) lut[i] = tlut[i];
  __syncthreads();

  {
    const int t  = tid;
    const int wi = t >> 4;
    const int sh = 30 - 2 * (t & 15);
    const unsigned mask = (t < 4) ? ((1u << (2 * t + 2)) - 1u) : 1023u;
    #pragma unroll
    for (int s = 0; s < 8; ++s) {
      unsigned lo = (unsigned)words[s * 16 + wi];
      unsigned hi = wi ? (unsigned)words[s * 16 + wi - 1] : 0u;
      unsigned long long comb = ((unsigned long long)hi << 32) | (unsigned long long)lo;
      unsigned st = ((unsigned)(comb >> sh)) & mask;
      float2 v = lut[st];
      buf[s * 512 + 2 * t]     = v.x + v.y;   // h=1 stage folded
      buf[s * 512 + 2 * t + 1] = v.x - v.y;
    }
  }
  __syncthreads();

  for (int h = 2; h < 4096; h <<= 1) {
    #pragma unroll
    for (int q = 0; q < 8; ++q) {
      int b = q * 256 + tid;
      int i = ((b & ~(h - 1)) << 1) | (b & (h - 1));
      float a = buf[i], c = buf[i + h];
      buf[i]     = a + c;
      buf[i + h] = a - c;
    }
    __syncthreads();
  }

  for (int it2 = 0; it2 < 2; ++it2) {
    int c0 = (it2 * 256 + tid) * 8;
    union { unsigned short us[8]; uint4 v; } p;
    #pragma unroll
    for (int e = 0; e < 8; ++e)
      p.us[e] = f2bf(buf[c0 + e] * SU[c0 + e] * 0.015625f);
    *(uint4*)(w + (size_t)r * IN_DIM + c0) = p.v;
  }

  #pragma unroll
  for (int rep = 0; rep < 4; ++rep) {
    size_t i = (((size_t)r * 4 + rep) * 256 + tid) * 8;
    float4 v0 = xv[rep * 2], v1 = xv[rep * 2 + 1];
    union { __hip_bfloat16 h[8]; uint4 u; } p;
    p.h[0] = __float2bfloat16(v0.x); p.h[1] = __float2bfloat16(v0.y);
    p.h[2] = __float2bfloat16(v0.z); p.h[3] = __float2bfloat16(v0.w);
    p.h[4] = __float2bfloat16(v1.x); p.h[5] = __float2bfloat16(v1.y);
    p.h[6] = __float2bfloat16(v1.z); p.h[7] = __float2bfloat16(v1.w);
    *(uint4*)(xb + i) = p.u;
  }
}

// ---------------- Pass 2a: FWHT64 over row-index low 6 bits (in place) ----------------
__global__ __launch_bounds__(256) void k_fwht64_lo(__hip_bfloat16* __restrict__ w)
{
  __shared__ float tile[64][65];
  const int tid = threadIdx.x;
  const int rb = blockIdx.y, cb = blockIdx.x;

  for (int it = 0; it < 2; ++it) {
    int chunk = it * 256 + tid;
    int rr = chunk >> 3, jc = chunk & 7;
    uint4 v = *(const uint4*)(w + (size_t)(rb * 64 + rr) * IN_DIM + cb * 64 + jc * 8);
    const unsigned short* u = (const unsigned short*)&v;
    #pragma unroll
    for (int e = 0; e < 8; ++e) tile[rr][jc * 8 + e] = bf2f(u[e]);
  }
  __syncthreads();

  const int c = tid & 63, qf = tid >> 6;
  for (int h = 1; h < 64; h <<= 1) {
    #pragma unroll
    for (int u = 0; u < 8; ++u) {
      int b = qf * 8 + u;
      int i = ((b & ~(h - 1)) << 1) | (b & (h - 1));
      float a = tile[i][c], d = tile[i + h][c];
      tile[i][c]     = a + d;
      tile[i + h][c] = a - d;
    }
    __syncthreads();
  }

  for (int it = 0; it < 2; ++it) {
    int chunk = it * 256 + tid;
    int rr = chunk >> 3, jc = chunk & 7;
    union { unsigned short us[8]; uint4 v; } p;
    #pragma unroll
    for (int e = 0; e < 8; ++e) p.us[e] = f2bf(tile[rr][jc * 8 + e]);
    *(uint4*)(w + (size_t)(rb * 64 + rr) * IN_DIM + cb * 64 + jc * 8) = p.v;
  }
}

// ---------------- Pass 2b: FWHT64 over row-index high 6 bits + SV * 1/64 ----------------
__global__ __launch_bounds__(256) void k_fwht64_hi(__hip_bfloat16* __restrict__ w,
                                                   const float* __restrict__ SV)
{
  __shared__ float tile[64][65];
  const int tid = threadIdx.x;
  const int r0 = blockIdx.y, cb = blockIdx.x;

  for (int it = 0; it < 2; ++it) {
    int chunk = it * 256 + tid;
    int r1 = chunk >> 3, jc = chunk & 7;
    uint4 v = *(const uint4*)(w + (size_t)(r0 + 64 * r1) * IN_DIM + cb * 64 + jc * 8);
    const unsigned short* u = (const unsigned short*)&v;
    #pragma unroll
    for (int e = 0; e < 8; ++e) tile[r1][jc * 8 + e] = bf2f(u[e]);
  }
  __syncthreads();

  const int c = tid & 63, qf = tid >> 6;
  for (int h = 1; h < 64; h <<= 1) {
    #pragma unroll
    for (int u = 0; u < 8; ++u) {
      int b = qf * 8 + u;
      int i = ((b & ~(h - 1)) << 1) | (b & (h - 1));
      float a = tile[i][c], d = tile[i + h][c];
      tile[i][c]     = a + d;
      tile[i + h][c] = a - d;
    }
    __syncthreads();
  }

  for (int it = 0; it < 2; ++it) {
    int chunk = it * 256 + tid;
    int r1 = chunk >> 3, jc = chunk & 7;
    int row = r0 + 64 * r1;
    float sv = SV[row] * 0.015625f;
    union { unsigned short us[8]; uint4 v; } p;
    #pragma unroll
    for (int e = 0; e < 8; ++e) p.us[e] = f2bf(tile[r1][jc * 8 + e] * sv);
    *(uint4*)(w + (size_t)row * IN_DIM + cb * 64 + jc * 8) = p.v;
  }
}

// ========== GEMM: 256x256, BK=32, one barrier per K-tile, frags fit 128 VGPR =========
// Frags per tile: fa[8]+fb[4] = 48 VGPR; double-buffered = 96 (+~20 addr) < 128 arch
// VGPRs (acc[8][4]=128 lives in the AGPR half). Race-free invariant (R9 discipline):
// phase(t): {STAGE4(t+2 -> buf t&1); RD_ALL(t+1 <- buf (t+1)&1); 32 MFMA on tile-t
// regs; vmcnt(0)+lgkmcnt(0); BAR}. All staged data complete and all frag reads
// drained before any wave crosses the barrier.
// Swizzle: row stride 64 B -> 2-bit XOR (chunk ^= row&3); frag reads ~4-way
// conflicted (1.58x, m136) but hidden under the ~1240-cyc MFMA cluster.
#define GBM 256
#define GBN 256
#define GBK 32
#define NT  (IN_DIM / GBK)   // 128 K-tiles

__global__ __launch_bounds__(512, 2) void k_gemm256(
    const __hip_bfloat16* __restrict__ X,   // [8192][4096]
    const __hip_bfloat16* __restrict__ W,   // [4096][4096]
    float* __restrict__ out)                // [8192][4096]
{
  extern __shared__ __hip_bfloat16 smem[];  // 65536 B
  __hip_bfloat16* As = smem;                // [2][256*32]
  __hip_bfloat16* Bs = smem + 2 * 8192;

  const int tid  = threadIdx.x;
  const int lane = tid & 63;
  const int wave = tid >> 6;
  const int wm   = wave >> 2;       // 0..1 (M)
  const int wn   = wave & 3;        // 0..3 (N)
  const int lm   = lane & 15;
  const int lq   = lane >> 4;       // 0..3 (k-chunk)
  const int s_rw = tid >> 2;        // staging row-within-128 0..127
  const int s_jj = tid & 3;         // staging 16B chunk 0..3

  // T1: bijective XCD swizzle (512 blocks)
  const int nwg  = gridDim.x * gridDim.y;
  const int cpx  = nwg >> 3;
  const int orig = blockIdx.y * gridDim.x + blockIdx.x;
  const int swz  = (orig & 7) * cpx + (orig >> 3);
  const int bx   = swz % gridDim.x;
  const int by   = swz / gridDim.x;
  const int m0 = by * GBM, n0 = bx * GBN;

  f32x4 acc[8][4] = {};

#define STAGE4(buf, kt) do {                                                  \
    _Pragma("unroll")                                                         \
    for (int u_ = 0; u_ < 2; ++u_) {                                          \
      int row_ = u_ * 128 + s_rw;                                             \
      int js_  = s_jj ^ (row_ & 3);                                           \
      gload_lds16(X + (size_t)(m0 + row_) * IN_DIM + (kt) * GBK + js_ * 8,    \
                  As + (buf) * 8192 + row_ * 32 + s_jj * 8);                  \
      gload_lds16(W + (size_t)(n0 + row_) * IN_DIM + (kt) * GBK + js_ * 8,    \
                  Bs + (buf) * 8192 + row_ * 32 + s_jj * 8);                  \
    }                                                                         \
  } while (0)

#define RD_ALL(FA, FB, BUF) do {                                              \
    const __hip_bfloat16* Ab_ = As + (BUF) * 8192;                            \
    const __hip_bfloat16* Bb_ = Bs + (BUF) * 8192;                            \
    _Pragma("unroll")                                                         \
    for (int mi2 = 0; mi2 < 8; ++mi2) {                                       \
      int r_ = wm * 128 + mi2 * 16 + lm;                                      \
      FA[mi2] = *(const bf16x8*)(Ab_ + r_ * 32 + ((lq ^ (r_ & 3)) << 3));     \
    }                                                                         \
    _Pragma("unroll")                                                         \
    for (int ni2 = 0; ni2 < 4; ++ni2) {                                       \
      int r_ = wn * 64 + ni2 * 16 + lm;                                       \
      FB[ni2] = *(const bf16x8*)(Bb_ + r_ * 32 + ((lq ^ (r_ & 3)) << 3));     \
    }                                                                         \
  } while (0)

#define MFMA_ALL(FA, FB) do {                                                 \
    _Pragma("unroll")                                                         \
    for (int mi2 = 0; mi2 < 8; ++mi2)                                         \
      _Pragma("unroll")                                                       \
      for (int ni2 = 0; ni2 < 4; ++ni2)                                       \
        acc[mi2][ni2] = __builtin_amdgcn_mfma_f32_16x16x32_bf16(              \
            FA[mi2], FB[ni2], acc[mi2][ni2], 0, 0, 0);                        \
  } while (0)

#define FENCE asm volatile("" ::: "memory")
#define BAR do { FENCE; __builtin_amdgcn_s_barrier(); FENCE; } while (0)
#define DRAIN_ALL do { asm volatile("s_waitcnt vmcnt(0) lgkmcnt(0)" ::: "memory"); } while (0)

  bf16x8 fa0[8], fb0[4], fa1[8], fb1[4];

  // prologue: stage tiles 0,1; drain (cross-wave invariant); read tile-0 frags
  STAGE4(0, 0);
  STAGE4(1, 1);
  DRAIN_ALL;
  BAR;                       // both tiles complete + visible to all waves
  RD_ALL(fa0, fb0, 0);
  asm volatile("s_waitcnt lgkmcnt(0)" ::: "memory");
  BAR;                       // tile-0 reads drained before anyone stages into buf0

  for (int it = 0; it < NT / 2; ++it) {
    const int t2 = (2 * it + 2 < NT) ? 2 * it + 2 : NT - 1;
    const int t3 = (2 * it + 3 < NT) ? 2 * it + 3 : NT - 1;

    // phase even (tile 2it): stage t2 -> buf0, read tile 2it+1 from buf1
    STAGE4(0, t2);
    RD_ALL(fa1, fb1, 1);
    __builtin_amdgcn_s_setprio(1);
    MFMA_ALL(fa0, fb0);
    __builtin_amdgcn_s_setprio(0);
    DRAIN_ALL;
    BAR;

    // phase odd (tile 2it+1): stage t3 -> buf1, read tile 2it+2 from buf0
    STAGE4(1, t3);
    RD_ALL(fa0, fb0, 0);
    __builtin_amdgcn_s_setprio(1);
    MFMA_ALL(fa1, fb1);
    __builtin_amdgcn_s_setprio(0);
    DRAIN_ALL;
    BAR;
  }

  // epilogue: C/D layout col = lane&15, row = (lane>>4)*4 + reg
  #pragma unroll
  for (int mi = 0; mi < 8; ++mi) {
    #pragma unroll
    for (int ni = 0; ni < 4; ++ni) {
      int col   = n0 + wn * 64 + ni * 16 + lm;
      int rbase = m0 + wm * 128 + mi * 16 + lq * 4;
      #pragma unroll
      for (int rg = 0; rg < 4; ++rg) {
        out[(size_t)(rbase + rg) * OUT_DIM + col] = acc[mi][ni][rg];
      }
    }
  }
#undef DRAIN_ALL
#undef BAR
#undef FENCE
#undef MFMA_ALL
#undef RD_ALL
#undef STAGE4
}

extern "C" void kernel_launch(void* const* d_in, const int* in_sizes, int n_in,
                              void* d_out, int out_size, void* d_ws, size_t ws_size,
                              hipStream_t stream) {
  (void)in_sizes; (void)n_in; (void)out_size; (void)ws_size;
  const float* x       = (const float*)d_in[0];
  const int*   trellis = (const int*)d_in[1];
  const float* tlut    = (const float*)d_in[2];
  const float* SU      = (const float*)d_in[3];
  const float* SV      = (const float*)d_in[4];
  float* out = (float*)d_out;

  __hip_bfloat16* Wd = (__hip_bfloat16*)d_ws;                                     // 32 MB
  __hip_bfloat16* Xb = (__hip_bfloat16*)((char*)d_ws + (size_t)32 * 1024 * 1024); // 64 MB

  k_decode_fwht_row<<<4096, 256, 0, stream>>>(trellis, (const float2*)tlut, SU, Wd, x, Xb);
  k_fwht64_lo<<<dim3(64, 64), 256, 0, stream>>>(Wd);
  k_fwht64_hi<<<dim3(64, 64), 256, 0, stream>>>(Wd, SV);

  hipFuncSetAttribute((const void*)k_gemm256,
                      hipFuncAttributeMaxDynamicSharedMemorySize, 65536);
  k_gemm256<<<dim3(IN_DIM / GBN, M_DIM / GBM), 512, 65536, stream>>>(Xb, Wd, out);
}

// Round 11
// 347.487 us; speedup vs baseline: 7.0671x; 1.0114x over previous
//
#include <hip/hip_runtime.h>
#include <hip/hip_bf16.h>
#include <stdint.h>

typedef __bf16 bf16x8 __attribute__((ext_vector_type(8)));
typedef float  f32x4  __attribute__((ext_vector_type(4)));

#define IN_DIM  4096
#define OUT_DIM 4096
#define M_DIM   8192

#define AS1 __attribute__((address_space(1)))
#define AS3 __attribute__((address_space(3)))

static __device__ __forceinline__ void gload_lds16(const void* g, void* l) {
  __builtin_amdgcn_global_load_lds((const AS1 void*)g, (AS3 void*)l, 16, 0, 0);
}
static __device__ __forceinline__ float bf2f(unsigned short u) {
  union { uint32_t i; float f; } c; c.i = (uint32_t)u << 16; return c.f;
}
static __device__ __forceinline__ unsigned short f2bf(float f) {
  __hip_bfloat16 h = __float2bfloat16(f); return *(const unsigned short*)&h;
}

// ------- Pass 1: decode + row FWHT(4096) + SU*1/64, with fused x->bf16 convert -------
__global__ __launch_bounds__(256) void k_decode_fwht_row(
    const int* __restrict__ trellis, const float2* __restrict__ tlut,
    const float* __restrict__ SU, __hip_bfloat16* __restrict__ w,
    const float* __restrict__ x, __hip_bfloat16* __restrict__ xb)
{
  __shared__ float buf[4096];
  __shared__ int words[128];
  __shared__ float2 lut[1024];
  const int tid = threadIdx.x;
  const int r = blockIdx.x;

  // issue X loads early; latency hides under trellis/LUT load + decode
  float4 xv[8];
  #pragma unroll
  for (int rep = 0; rep < 4; ++rep) {
    size_t i = (((size_t)r * 4 + rep) * 256 + tid) * 8;
    xv[rep * 2]     = *(const float4*)(x + i);
    xv[rep * 2 + 1] = *(const float4*)(x + i + 4);
  }

  if (tid < 128) words[tid] = trellis[r * 128 + tid];
  for (int i = tid; i < 1024; i += 256) lut[i] = tlut[i];
  __syncthreads();

  {
    const int t  = tid;
    const int wi = t >> 4;
    const int sh = 30 - 2 * (t & 15);
    const unsigned mask = (t < 4) ? ((1u << (2 * t + 2)) - 1u) : 1023u;
    #pragma unroll
    for (int s = 0; s < 8; ++s) {
      unsigned lo = (unsigned)words[s * 16 + wi];
      unsigned hi = wi ? (unsigned)words[s * 16 + wi - 1] : 0u;
      unsigned long long comb = ((unsigned long long)hi << 32) | (unsigned long long)lo;
      unsigned st = ((unsigned)(comb >> sh)) & mask;
      float2 v = lut[st];
      buf[s * 512 + 2 * t]     = v.x + v.y;   // h=1 stage folded
      buf[s * 512 + 2 * t + 1] = v.x - v.y;
    }
  }
  __syncthreads();

  for (int h = 2; h < 4096; h <<= 1) {
    #pragma unroll
    for (int q = 0; q < 8; ++q) {
      int b = q * 256 + tid;
      int i = ((b & ~(h - 1)) << 1) | (b & (h - 1));
      float a = buf[i], c = buf[i + h];
      buf[i]     = a + c;
      buf[i + h] = a - c;
    }
    __syncthreads();
  }

  for (int it2 = 0; it2 < 2; ++it2) {
    int c0 = (it2 * 256 + tid) * 8;
    union { unsigned short us[8]; uint4 v; } p;
    #pragma unroll
    for (int e = 0; e < 8; ++e)
      p.us[e] = f2bf(buf[c0 + e] * SU[c0 + e] * 0.015625f);
    *(uint4*)(w + (size_t)r * IN_DIM + c0) = p.v;
  }

  #pragma unroll
  for (int rep = 0; rep < 4; ++rep) {
    size_t i = (((size_t)r * 4 + rep) * 256 + tid) * 8;
    float4 v0 = xv[rep * 2], v1 = xv[rep * 2 + 1];
    union { __hip_bfloat16 h[8]; uint4 u; } p;
    p.h[0] = __float2bfloat16(v0.x); p.h[1] = __float2bfloat16(v0.y);
    p.h[2] = __float2bfloat16(v0.z); p.h[3] = __float2bfloat16(v0.w);
    p.h[4] = __float2bfloat16(v1.x); p.h[5] = __float2bfloat16(v1.y);
    p.h[6] = __float2bfloat16(v1.z); p.h[7] = __float2bfloat16(v1.w);
    *(uint4*)(xb + i) = p.u;
  }
}

// ---------------- Pass 2a: FWHT64 over row-index low 6 bits (in place) ----------------
__global__ __launch_bounds__(256) void k_fwht64_lo(__hip_bfloat16* __restrict__ w)
{
  __shared__ float tile[64][65];
  const int tid = threadIdx.x;
  const int rb = blockIdx.y, cb = blockIdx.x;

  for (int it = 0; it < 2; ++it) {
    int chunk = it * 256 + tid;
    int rr = chunk >> 3, jc = chunk & 7;
    uint4 v = *(const uint4*)(w + (size_t)(rb * 64 + rr) * IN_DIM + cb * 64 + jc * 8);
    const unsigned short* u = (const unsigned short*)&v;
    #pragma unroll
    for (int e = 0; e < 8; ++e) tile[rr][jc * 8 + e] = bf2f(u[e]);
  }
  __syncthreads();

  const int c = tid & 63, qf = tid >> 6;
  for (int h = 1; h < 64; h <<= 1) {
    #pragma unroll
    for (int u = 0; u < 8; ++u) {
      int b = qf * 8 + u;
      int i = ((b & ~(h - 1)) << 1) | (b & (h - 1));
      float a = tile[i][c], d = tile[i + h][c];
      tile[i][c]     = a + d;
      tile[i + h][c] = a - d;
    }
    __syncthreads();
  }

  for (int it = 0; it < 2; ++it) {
    int chunk = it * 256 + tid;
    int rr = chunk >> 3, jc = chunk & 7;
    union { unsigned short us[8]; uint4 v; } p;
    #pragma unroll
    for (int e = 0; e < 8; ++e) p.us[e] = f2bf(tile[rr][jc * 8 + e]);
    *(uint4*)(w + (size_t)(rb * 64 + rr) * IN_DIM + cb * 64 + jc * 8) = p.v;
  }
}

// ---------------- Pass 2b: FWHT64 over row-index high 6 bits + SV * 1/64 ----------------
__global__ __launch_bounds__(256) void k_fwht64_hi(__hip_bfloat16* __restrict__ w,
                                                   const float* __restrict__ SV)
{
  __shared__ float tile[64][65];
  const int tid = threadIdx.x;
  const int r0 = blockIdx.y, cb = blockIdx.x;

  for (int it = 0; it < 2; ++it) {
    int chunk = it * 256 + tid;
    int r1 = chunk >> 3, jc = chunk & 7;
    uint4 v = *(const uint4*)(w + (size_t)(r0 + 64 * r1) * IN_DIM + cb * 64 + jc * 8);
    const unsigned short* u = (const unsigned short*)&v;
    #pragma unroll
    for (int e = 0; e < 8; ++e) tile[r1][jc * 8 + e] = bf2f(u[e]);
  }
  __syncthreads();

  const int c = tid & 63, qf = tid >> 6;
  for (int h = 1; h < 64; h <<= 1) {
    #pragma unroll
    for (int u = 0; u < 8; ++u) {
      int b = qf * 8 + u;
      int i = ((b & ~(h - 1)) << 1) | (b & (h - 1));
      float a = tile[i][c], d = tile[i + h][c];
      tile[i][c]     = a + d;
      tile[i + h][c] = a - d;
    }
    __syncthreads();
  }

  for (int it = 0; it < 2; ++it) {
    int chunk = it * 256 + tid;
    int r1 = chunk >> 3, jc = chunk & 7;
    int row = r0 + 64 * r1;
    float sv = SV[row] * 0.015625f;
    union { unsigned short us[8]; uint4 v; } p;
    #pragma unroll
    for (int e = 0; e < 8; ++e) p.us[e] = f2bf(tile[r1][jc * 8 + e] * sv);
    *(uint4*)(w + (size_t)row * IN_DIM + cb * 64 + jc * 8) = p.v;
  }
}

// ===== GEMM: 256x256, BK=32, one barrier/K-tile, 128B-line paired-row swizzle ========
// LDS layout (per tile, A and B identically): rows packed in PAIRS into 128B lines.
//   line = row>>1 (0..127), pos = ((row&1)*4 + kchunk) ^ (line&7), addr = line*128B + pos*16B.
// 128B = exact 32-bank wrap -> bank set depends only on pos; 3-bit XOR spreads the
// 16 rows of a frag read over all 8 pos slots 2-way (free, m136) — R7-verified geometry.
// Staging is global_load_lds-legal: LDS dest linear in slot s=(line*8+pos); global
// source is the inverse perm: tmp=pos^(line&7); row=line*2+(tmp>>2); jc=tmp&3.
// Race-free discipline unchanged from R10: phase(t) = {STAGE4(t+2 -> buf t&1);
// RD_ALL(t+1 <- buf (t+1)&1); 32 MFMA tile-t; vmcnt(0)+lgkmcnt(0); BAR}.
#define GBM 256
#define GBN 256
#define GBK 32
#define NT  (IN_DIM / GBK)   // 128 K-tiles

__global__ __launch_bounds__(512, 2) void k_gemm256(
    const __hip_bfloat16* __restrict__ X,   // [8192][4096]
    const __hip_bfloat16* __restrict__ W,   // [4096][4096]
    float* __restrict__ out)                // [8192][4096]
{
  extern __shared__ __hip_bfloat16 smem[];  // 65536 B
  __hip_bfloat16* As = smem;                // [2][8192 elems]
  __hip_bfloat16* Bs = smem + 2 * 8192;

  const int tid  = threadIdx.x;
  const int lane = tid & 63;
  const int wave = tid >> 6;
  const int wm   = wave >> 2;       // 0..1 (M)
  const int wn   = wave & 3;        // 0..3 (N)
  const int lm   = lane & 15;
  const int lq   = lane >> 4;       // 0..3 (k-chunk)

  // T1: bijective XCD swizzle (512 blocks)
  const int nwg  = gridDim.x * gridDim.y;
  const int cpx  = nwg >> 3;
  const int orig = blockIdx.y * gridDim.x + blockIdx.x;
  const int swz  = (orig & 7) * cpx + (orig >> 3);
  const int bx   = swz % gridDim.x;
  const int by   = swz / gridDim.x;
  const int m0 = by * GBM, n0 = bx * GBN;

  f32x4 acc[8][4] = {};

  // staging: slot s in [0,1024) per matrix; each thread covers s = u*512 + tid, u=0,1
#define STAGE4(buf, kt) do {                                                  \
    _Pragma("unroll")                                                         \
    for (int u_ = 0; u_ < 2; ++u_) {                                          \
      int s_    = u_ * 512 + tid;                                             \
      int line_ = s_ >> 3, pos_ = s_ & 7;                                     \
      int tmp_  = pos_ ^ (line_ & 7);                                         \
      int row_  = line_ * 2 + (tmp_ >> 2);                                    \
      int jc_   = tmp_ & 3;                                                   \
      gload_lds16(X + (size_t)(m0 + row_) * IN_DIM + (kt) * GBK + jc_ * 8,    \
                  As + (buf) * 8192 + s_ * 8);                                \
      gload_lds16(W + (size_t)(n0 + row_) * IN_DIM + (kt) * GBK + jc_ * 8,    \
                  Bs + (buf) * 8192 + s_ * 8);                                \
    }                                                                         \
  } while (0)

#define RD_ALL(FA, FB, BUF) do {                                              \
    const __hip_bfloat16* Ab_ = As + (BUF) * 8192;                            \
    const __hip_bfloat16* Bb_ = Bs + (BUF) * 8192;                            \
    _Pragma("unroll")                                                         \
    for (int mi2 = 0; mi2 < 8; ++mi2) {                                       \
      int r_ = wm * 128 + mi2 * 16 + lm;                                      \
      int ln_ = r_ >> 1;                                                      \
      int po_ = (((r_ & 1) << 2) | lq) ^ (ln_ & 7);                           \
      FA[mi2] = *(const bf16x8*)(Ab_ + ln_ * 64 + po_ * 8);                   \
    }                                                                         \
    _Pragma("unroll")                                                         \
    for (int ni2 = 0; ni2 < 4; ++ni2) {                                       \
      int r_ = wn * 64 + ni2 * 16 + lm;                                       \
      int ln_ = r_ >> 1;                                                      \
      int po_ = (((r_ & 1) << 2) | lq) ^ (ln_ & 7);                           \
      FB[ni2] = *(const bf16x8*)(Bb_ + ln_ * 64 + po_ * 8);                   \
    }                                                                         \
  } while (0)

#define MFMA_ALL(FA, FB) do {                                                 \
    _Pragma("unroll")                                                         \
    for (int mi2 = 0; mi2 < 8; ++mi2)                                         \
      _Pragma("unroll")                                                       \
      for (int ni2 = 0; ni2 < 4; ++ni2)                                       \
        acc[mi2][ni2] = __builtin_amdgcn_mfma_f32_16x16x32_bf16(              \
            FA[mi2], FB[ni2], acc[mi2][ni2], 0, 0, 0);                        \
  } while (0)

#define FENCE asm volatile("" ::: "memory")
#define BAR do { FENCE; __builtin_amdgcn_s_barrier(); FENCE; } while (0)
#define DRAIN_ALL do { asm volatile("s_waitcnt vmcnt(0) lgkmcnt(0)" ::: "memory"); } while (0)

  bf16x8 fa0[8], fb0[4], fa1[8], fb1[4];

  // prologue: stage tiles 0,1; drain (cross-wave invariant); read tile-0 frags
  STAGE4(0, 0);
  STAGE4(1, 1);
  DRAIN_ALL;
  BAR;                       // both tiles complete + visible to all waves
  RD_ALL(fa0, fb0, 0);
  asm volatile("s_waitcnt lgkmcnt(0)" ::: "memory");
  BAR;                       // tile-0 reads drained before anyone stages into buf0

  for (int it = 0; it < NT / 2; ++it) {
    const int t2 = (2 * it + 2 < NT) ? 2 * it + 2 : NT - 1;
    const int t3 = (2 * it + 3 < NT) ? 2 * it + 3 : NT - 1;

    // phase even (tile 2it): stage t2 -> buf0, read tile 2it+1 from buf1
    STAGE4(0, t2);
    RD_ALL(fa1, fb1, 1);
    __builtin_amdgcn_s_setprio(1);
    MFMA_ALL(fa0, fb0);
    __builtin_amdgcn_s_setprio(0);
    DRAIN_ALL;
    BAR;

    // phase odd (tile 2it+1): stage t3 -> buf1, read tile 2it+2 from buf0
    STAGE4(1, t3);
    RD_ALL(fa0, fb0, 0);
    __builtin_amdgcn_s_setprio(1);
    MFMA_ALL(fa1, fb1);
    __builtin_amdgcn_s_setprio(0);
    DRAIN_ALL;
    BAR;
  }

  // epilogue: C/D layout col = lane&15, row = (lane>>4)*4 + reg
  #pragma unroll
  for (int mi = 0; mi < 8; ++mi) {
    #pragma unroll
    for (int ni = 0; ni < 4; ++ni) {
      int col   = n0 + wn * 64 + ni * 16 + lm;
      int rbase = m0 + wm * 128 + mi * 16 + lq * 4;
      #pragma unroll
      for (int rg = 0; rg < 4; ++rg) {
        out[(size_t)(rbase + rg) * OUT_DIM + col] = acc[mi][ni][rg];
      }
    }
  }
#undef DRAIN_ALL
#undef BAR
#undef FENCE
#undef MFMA_ALL
#undef RD_ALL
#undef STAGE4
}

extern "C" void kernel_launch(void* const* d_in, const int* in_sizes, int n_in,
                              void* d_out, int out_size, void* d_ws, size_t ws_size,
                              hipStream_t stream) {
  (void)in_sizes; (void)n_in; (void)out_size; (void)ws_size;
  const float* x       = (const float*)d_in[0];
  const int*   trellis = (const int*)d_in[1];
  const float* tlut    = (const float*)d_in[2];
  const float* SU      = (const float*)d_in[3];
  const float* SV      = (const float*)d_in[4];
  float* out = (float*)d_out;

  __hip_bfloat16* Wd = (__hip_bfloat16*)d_ws;                                     // 32 MB
  __hip_bfloat16* Xb = (__hip_bfloat16*)((char*)d_ws + (size_t)32 * 1024 * 1024); // 64 MB

  k_decode_fwht_row<<<4096, 256, 0, stream>>>(trellis, (const float2*)tlut, SU, Wd, x, Xb);
  k_fwht64_lo<<<dim3(64, 64), 256, 0, stream>>>(Wd);
  k_fwht64_hi<<<dim3(64, 64), 256, 0, stream>>>(Wd, SV);

  hipFuncSetAttribute((const void*)k_gemm256,
                      hipFuncAttributeMaxDynamicSharedMemorySize, 65536);
  k_gemm256<<<dim3(IN_DIM / GBN, M_DIM / GBM), 512, 65536, stream>>>(Xb, Wd, out);
}